// Round 8
// baseline (8800.604 us; speedup 1.0000x reference)
//
#include <hip/hip_runtime.h>
#include <stdint.h>

// ---------- GEMM fp32: C[M][N] = A[M][K] @ B[K][N] ----------
// Block: 16 m-rows x 256 n-cols. Lane n-contiguous -> coalesced B; A broadcast.
__global__ __launch_bounds__(256) void gemm_f32_v8(const float* __restrict__ A,
                                                   const float* __restrict__ B,
                                                   float* __restrict__ C,
                                                   int M, int N, int K) {
    int nb = N >> 8;
    int bn = blockIdx.x % nb;
    int m0 = (blockIdx.x / nb) << 4;
    int n = (bn << 8) + threadIdx.x;
    float acc[16];
    for (int r = 0; r < 16; r++) acc[r] = 0.f;
    const float* Ab = A + (size_t)m0 * K;
    for (int k = 0; k < K; k++) {
        float bv = B[(size_t)k * N + n];
        for (int r = 0; r < 16; r++)
            acc[r] += Ab[(size_t)r * K + k] * bv;
    }
    for (int r = 0; r < 16; r++)
        C[(size_t)(m0 + r) * N + n] = acc[r];
}

// ---------- RoPE fp32 in-place on q,k halves of qkv [4096][6144] ----------
// Head h at cols part*2048 + h*128; adjacent pair (2*d2, 2*d2+1) rotated by
// freqs[s][0][d2][{cos,sin}] — matches reference reshape(B,S,2H,D/2,2).
__global__ __launch_bounds__(256) void rope_f32_v8(float* __restrict__ qkv,
                                                   const float* __restrict__ freqs) {
    int idx = blockIdx.x * 256 + threadIdx.x;  // 4096*2048 (row, pair)
    int row = idx >> 11;
    int p = idx & 2047;
    int part = p >> 10;       // 0=q, 1=k
    int rem = p & 1023;
    int h = rem >> 6;         // head (64 pairs per head)
    int d2 = rem & 63;
    int s = row & 2047;       // row = b*2048 + s
    size_t base = (size_t)row * 6144 + part * 2048 + h * 128 + 2 * d2;
    float c = freqs[(s * 64 + d2) * 2 + 0];
    float sn = freqs[(s * 64 + d2) * 2 + 1];
    float x0 = qkv[base];
    float x1 = qkv[base + 1];
    qkv[base] = x0 * c - x1 * sn;
    qkv[base + 1] = x1 * c + x0 * sn;
}

// ---------- causal flash attention, fp32 ----------
// grid: b(2) x h(16) x qb(32 blocks of 64 q-rows) = 1024 blocks, 256 threads.
// 4 lanes per q-row; each lane owns 32 of 128 dims. K-tile = 32 keys in LDS.
__global__ __launch_bounds__(256) void attn_f32_v8(const float* __restrict__ qkv,
                                                   float* __restrict__ out) {
    __shared__ float Ks[32][132];
    __shared__ float Vs[32][132];
    int t = threadIdx.x;
    int row_l = t >> 2;          // 0..63
    int dseg = t & 3;            // 0..3
    int bx = blockIdx.x;
    int qb = bx & 31;
    int h = (bx >> 5) & 15;
    int b = bx >> 9;
    int q = qb * 64 + row_l;
    const float scale = 0.08838834764831845f;  // 1/sqrt(128)
    size_t rowbase = (size_t)(b * 2048 + q) * 6144 + h * 128 + dseg * 32;

    float qv[32];
    for (int i = 0; i < 32; i++) qv[i] = qkv[rowbase + i];

    float m = -1e30f, l = 0.f;
    float o[32];
    for (int i = 0; i < 32; i++) o[i] = 0.f;

    int ntile = (qb + 1) * 2;  // keys 0 .. qb*64+63 in tiles of 32
    for (int kt = 0; kt < ntile; kt++) {
        int kbase = kt * 32;
        __syncthreads();  // prior iter's LDS reads done
        for (int i = 0; i < 16; i++) {
            int e = t * 16 + i;          // 32 keys x 128 dims
            int kk = e >> 7, dd = e & 127;
            size_t kr = (size_t)(b * 2048 + kbase + kk) * 6144 + h * 128 + dd;
            Ks[kk][dd] = qkv[kr + 2048];
            Vs[kk][dd] = qkv[kr + 4096];
        }
        __syncthreads();

        float s[32];
        for (int kk = 0; kk < 32; kk++) {
            float acc = 0.f;
            for (int i = 0; i < 32; i++) acc += qv[i] * Ks[kk][dseg * 32 + i];
            acc += __shfl_xor(acc, 1, 64);
            acc += __shfl_xor(acc, 2, 64);
            int key = kbase + kk;
            s[kk] = (key <= q) ? acc * scale : -1e30f;
        }
        float rmax = -1e30f;
        for (int kk = 0; kk < 32; kk++) rmax = fmaxf(rmax, s[kk]);
        float mnew = fmaxf(m, rmax);
        float alpha = __expf(m - mnew);
        m = mnew;
        float rsum = 0.f;
        for (int kk = 0; kk < 32; kk++) {
            s[kk] = __expf(s[kk] - mnew);
            rsum += s[kk];
        }
        l = l * alpha + rsum;
        for (int i = 0; i < 32; i++) o[i] *= alpha;
        for (int kk = 0; kk < 32; kk++) {
            float p = s[kk];
            for (int i = 0; i < 32; i++) o[i] += p * Vs[kk][dseg * 32 + i];
        }
    }

    float inv = 1.f / l;
    size_t outbase = (size_t)(b * 2048 + q) * 2048 + h * 128 + dseg * 32;
    for (int i = 0; i < 32; i++) out[outbase + i] = o[i] * inv;
}

extern "C" void kernel_launch(void* const* d_in, const int* in_sizes, int n_in,
                              void* d_out, int out_size, void* d_ws, size_t ws_size,
                              hipStream_t stream) {
    // All inputs fp32 per the reference; OUTPUT IS FP32 TOO (reference returns
    // float32; harness rule: "bfloat16 -> __hip_bfloat16*, else float*").
    const float* x = nullptr;      // 2*2048*2048 = 8388608
    const float* Wqkv = nullptr;   // 2048*6144  = 12582912
    const float* Wo = nullptr;     // 2048*2048  = 4194304
    const float* freqs = nullptr;  // 2048*64*2  = 262144
    for (int i = 0; i < n_in; i++) {
        switch (in_sizes[i]) {
            case 8388608:  x = (const float*)d_in[i]; break;
            case 12582912: Wqkv = (const float*)d_in[i]; break;
            case 4194304:  Wo = (const float*)d_in[i]; break;
            case 262144:   freqs = (const float*)d_in[i]; break;
        }
    }
    if (!x) x = (const float*)d_in[0];
    if (!Wqkv) Wqkv = (const float*)d_in[1];
    if (!Wo) Wo = (const float*)d_in[2];
    if (!freqs) freqs = (const float*)d_in[3];

    float* out = (float*)d_out;  // [4096][2048] fp32
    char* ws = (char*)d_ws;
    const size_t MB = 1 << 20;

    float* qkv  = (float*)(ws);            // 4096*6144*4 = 96 MB
    float* attn = (float*)(ws + 96 * MB);  // 4096*2048*4 = 32 MB (total 128 MB)

    // qkv = x @ Wqkv : [4096][6144]
    gemm_f32_v8<<<(4096 / 16) * (6144 / 256), 256, 0, stream>>>(x, Wqkv, qkv, 4096, 6144, 2048);
    // RoPE on q,k halves
    rope_f32_v8<<<(4096 * 2048) / 256, 256, 0, stream>>>(qkv, freqs);
    // causal SDPA -> attn [4096][2048]
    attn_f32_v8<<<2 * 16 * 32, 256, 0, stream>>>(qkv, attn);
    // out = attn @ Wo : [4096][2048], fp32 store
    gemm_f32_v8<<<(4096 / 16) * (2048 / 256), 256, 0, stream>>>(attn, Wo, out, 4096, 2048, 2048);
}